// Round 7
// baseline (225.504 us; speedup 1.0000x reference)
//
#include <hip/hip_runtime.h>
#include <math.h>

#define MARGIN  23.0f
#define MARGIN2 529.0f   // 23^2, exact in f32
#define DIM 256
#define NUM_POS 100000
#define NUM_NEG 100000

#define BLOCK 256
#define WAVES_PER_BLOCK (BLOCK / 64)
#define NBLOCKS 1792                     // 7 blocks/CU x 256 CUs, all co-resident
#define NW (NBLOCKS * WAVES_PER_BLOCK)   // 7168 waves
#define GP (NUM_POS / 4)                 // 25000 pos groups (4 rows each)
#define GTOT ((NUM_POS + NUM_NEG) / 4)   // 50000 groups total

typedef float v4f __attribute__((ext_vector_type(4)));

// Stage 1, R7: identical structure to R5 (16 lanes/row, 4 rows/wave-iter,
// static contiguous partition, depth-1 prefetch) with ONE change:
// CACHED loads instead of non-temporal. Rationale: the harness's restore
// memcpy rewrites the full 205 MB input through L2/L3 right before launch;
// R1-R3 measured FETCH_SIZE=100 MB (51% L3 hit) with cached reads. nt loads
// forfeit those hits and stream all 205 MB from HBM at the observed
// ~3.6 TB/s. A/B: this round isolates the nt variable.
//
// ws layout (floats, all SQUARED distances):
//   ws[0]                       = d_pos[0]^2 fallback
//   ws[1 .. NBLOCKS]            = per-block pos max (masked)
//   ws[1+NBLOCKS .. 2*NBLOCKS]  = per-block neg min
__global__ __launch_bounds__(BLOCK, 7) void triplet_stage1(
    const float* __restrict__ anchor,
    const float* __restrict__ pos,
    const float* __restrict__ neg,
    float* __restrict__ ws) {
  __shared__ float s_pos[WAVES_PER_BLOCK];
  __shared__ float s_neg[WAVES_PER_BLOCK];

  const int lane = threadIdx.x & 63;
  const int wid  = threadIdx.x >> 6;
  const int t    = lane & 15;   // segment within row
  const int q    = lane >> 4;   // which row of the group's 4

  // Anchor fragments (reused; cached loads).
  const v4f* af = reinterpret_cast<const v4f*>(anchor);
  const v4f a0 = af[t];
  const v4f a1 = af[t + 16];
  const v4f a2 = af[t + 32];
  const v4f a3 = af[t + 48];

  float pmax = -INFINITY;  // squared space
  float nmin =  INFINITY;

  // Static contiguous partition of GTOT groups over NW waves.
  const int w   = blockIdx.x * WAVES_PER_BLOCK + wid;
  const int qg  = GTOT / NW;                  // 6
  const int rg  = GTOT - qg * NW;             // 6992
  const int start = w * qg + (w < rg ? w : rg);
  const int count = qg + (w < rg ? 1 : 0);

  // Depth-1 software pipeline over the wave's contiguous range.
  int g = start;
  v4f p0, p1, p2, p3;
  {
    const float* base = (g < GP) ? (pos + (size_t)g * 4 * DIM)
                                 : (neg + (size_t)(g - GP) * 4 * DIM);
    const v4f* rp = reinterpret_cast<const v4f*>(base) + (size_t)q * (DIM / 4);
    p0 = rp[t];
    p1 = rp[t + 16];
    p2 = rp[t + 32];
    p3 = rp[t + 48];
  }

  for (int i = 0; i < count; ++i) {
    v4f n0, n1, n2, n3;
    if (i + 1 < count) {  // prefetch next group before reducing current
      const int gn = g + 1;
      const float* base = (gn < GP) ? (pos + (size_t)gn * 4 * DIM)
                                    : (neg + (size_t)(gn - GP) * 4 * DIM);
      const v4f* rp = reinterpret_cast<const v4f*>(base) + (size_t)q * (DIM / 4);
      n0 = rp[t];
      n1 = rp[t + 16];
      n2 = rp[t + 32];
      n3 = rp[t + 48];
    }

    v4f d0 = a0 - p0, d1 = a1 - p1, d2 = a2 - p2, d3 = a3 - p3;
    float s = (d0.x * d0.x + d0.y * d0.y + d0.z * d0.z + d0.w * d0.w) +
              (d1.x * d1.x + d1.y * d1.y + d1.z * d1.z + d1.w * d1.w) +
              (d2.x * d2.x + d2.y * d2.y + d2.z * d2.z + d2.w * d2.w) +
              (d3.x * d3.x + d3.y * d3.y + d3.z * d3.z + d3.w * d3.w);
    // Complete 4 row-sums with 4 shuffles (within-16 butterfly).
    s += __shfl_xor(s, 1, 64);
    s += __shfl_xor(s, 2, 64);
    s += __shfl_xor(s, 4, 64);
    s += __shfl_xor(s, 8, 64);

    if (g < GP) {
      if (g == 0 && lane == 0) ws[0] = s;  // row 0 fallback (squared)
      if (s < MARGIN2) pmax = fmaxf(pmax, s);
    } else {
      nmin = fminf(nmin, s);
    }

    p0 = n0; p1 = n1; p2 = n2; p3 = n3;
    ++g;
  }

  // Cross-quarter combine (lanes within a quarter hold identical values).
  pmax = fmaxf(pmax, __shfl_xor(pmax, 16, 64));
  pmax = fmaxf(pmax, __shfl_xor(pmax, 32, 64));
  nmin = fminf(nmin, __shfl_xor(nmin, 16, 64));
  nmin = fminf(nmin, __shfl_xor(nmin, 32, 64));

  if (lane == 0) {
    s_pos[wid] = pmax;
    s_neg[wid] = nmin;
  }
  __syncthreads();

  if (threadIdx.x == 0) {
    float pm = s_pos[0];
    float nm = s_neg[0];
    #pragma unroll
    for (int i = 1; i < WAVES_PER_BLOCK; ++i) {
      pm = fmaxf(pm, s_pos[i]);
      nm = fminf(nm, s_neg[i]);
    }
    ws[1 + blockIdx.x] = pm;
    ws[1 + NBLOCKS + blockIdx.x] = nm;
  }
}

// Stage 2: reduce NBLOCKS partials (squared space), sqrt once, write loss.
__global__ __launch_bounds__(BLOCK) void triplet_stage2(
    const float* __restrict__ ws,
    float* __restrict__ out) {
  __shared__ float s_pos[WAVES_PER_BLOCK];
  __shared__ float s_neg[WAVES_PER_BLOCK];

  const int lane = threadIdx.x & 63;
  const int wid  = threadIdx.x >> 6;

  float pm = -INFINITY;
  float nm =  INFINITY;
  for (int i = threadIdx.x; i < NBLOCKS; i += BLOCK) {
    pm = fmaxf(pm, ws[1 + i]);
    nm = fminf(nm, ws[1 + NBLOCKS + i]);
  }
  #pragma unroll
  for (int off = 32; off > 0; off >>= 1) {
    pm = fmaxf(pm, __shfl_xor(pm, off, 64));
    nm = fminf(nm, __shfl_xor(nm, off, 64));
  }
  if (lane == 0) {
    s_pos[wid] = pm;
    s_neg[wid] = nm;
  }
  __syncthreads();
  if (threadIdx.x == 0) {
    float fpm = s_pos[0];
    float fnm = s_neg[0];
    #pragma unroll
    for (int i = 1; i < WAVES_PER_BLOCK; ++i) {
      fpm = fmaxf(fpm, s_pos[i]);
      fnm = fminf(fnm, s_neg[i]);
    }
    if (fpm == -INFINITY) fpm = ws[0];  // no positive under margin -> index 0
    out[0] = fmaxf(sqrtf(fpm) - sqrtf(fnm) + MARGIN, 0.0f);
  }
}

extern "C" void kernel_launch(void* const* d_in, const int* in_sizes, int n_in,
                              void* d_out, int out_size, void* d_ws, size_t ws_size,
                              hipStream_t stream) {
  const float* anchor = (const float*)d_in[0];
  const float* pos    = (const float*)d_in[1];
  const float* neg    = (const float*)d_in[2];
  float* out = (float*)d_out;
  float* ws  = (float*)d_ws;

  triplet_stage1<<<NBLOCKS, BLOCK, 0, stream>>>(anchor, pos, neg, ws);
  triplet_stage2<<<1, BLOCK, 0, stream>>>(ws, out);
}